// Round 14
// baseline (353.904 us; speedup 1.0000x reference)
//
#include <hip/hip_runtime.h>

typedef short bf16x8 __attribute__((ext_vector_type(8)));      // 8 bf16 in 4 VGPRs
typedef float f32x4 __attribute__((ext_vector_type(4)));
typedef unsigned short ushort4v __attribute__((ext_vector_type(4)));
typedef unsigned short ushort8 __attribute__((ext_vector_type(8)));

#define DEVI static __device__ __forceinline__

DEVI unsigned short f2bf(float f) {               // RTNE fp32 -> bf16
    unsigned u = __float_as_uint(f);
    u += 0x7FFFu + ((u >> 16) & 1u);
    return (unsigned short)(u >> 16);
}

DEVI unsigned cvtpk(float lo, float hi) {         // packed fp32x2 -> bf16x2 (RNE)
    unsigned r;
    asm("v_cvt_pk_bf16_f32 %0, %1, %2" : "=v"(r) : "v"(lo), "v"(hi));
    return r;
}

typedef __attribute__((address_space(3))) unsigned int* lds_ptr_t;
typedef const __attribute__((address_space(1))) unsigned int* gbl_ptr_t;
#define GLDS(gp, lp) __builtin_amdgcn_global_load_lds((gbl_ptr_t)(gp), (lds_ptr_t)(lp), 16, 0, 0)

// ---------------- fp32 -> bf16 converts ----------------
__global__ void cvt_kernel(const float* __restrict__ src, unsigned short* __restrict__ dst, int n) {
    int i = (blockIdx.x * 256 + threadIdx.x) * 4;
    if (i >= n) return;
    float4 v = *(const float4*)(src + i);
    ushort4v o;
    o.x = f2bf(v.x); o.y = f2bf(v.y); o.z = f2bf(v.z); o.w = f2bf(v.w);
    *(ushort4v*)(dst + i) = o;
}

__global__ void cvt2_kernel(const float* __restrict__ s0, unsigned short* __restrict__ d0, int n0,
                            const float* __restrict__ s1, unsigned short* __restrict__ d1, int n1) {
    int idx = blockIdx.x * 256 + threadIdx.x;
    const int c0 = n0 >> 2;
    const float* src; unsigned short* dst; int i;
    if (idx < c0) { src = s0; dst = d0; i = idx * 4; }
    else {
        i = (idx - c0) * 4;
        if (i >= n1) return;
        src = s1; dst = d1;
    }
    float4 v = *(const float4*)(src + i);
    ushort4v o;
    o.x = f2bf(v.x); o.y = f2bf(v.y); o.z = f2bf(v.z); o.w = f2bf(v.w);
    *(ushort4v*)(dst + i) = o;
}

// all 7 tensors in one launch
__global__ void cvt4_kernel(const float* __restrict__ q, const float* __restrict__ k,
                            const float* __restrict__ v, const float* __restrict__ wq,
                            const float* __restrict__ wk, const float* __restrict__ wv,
                            const float* __restrict__ wo, unsigned short* __restrict__ dq,
                            unsigned short* __restrict__ dk, unsigned short* __restrict__ dv,
                            unsigned short* __restrict__ dwq, unsigned short* __restrict__ dwk,
                            unsigned short* __restrict__ dwv, unsigned short* __restrict__ dwo) {
    int idx = blockIdx.x * 256 + threadIdx.x;
    const float* src; unsigned short* dst; int base;
    if (idx < 1048576) { src = q; dst = dq; base = idx; }
    else if (idx < 2097152) { src = k; dst = dk; base = idx - 1048576; }
    else if (idx < 3145728) { src = v; dst = dv; base = idx - 2097152; }
    else if (idx < 3407872) { src = wq; dst = dwq; base = idx - 3145728; }
    else if (idx < 3670016) { src = wk; dst = dwk; base = idx - 3407872; }
    else if (idx < 3932160) { src = wv; dst = dwv; base = idx - 3670016; }
    else { src = wo; dst = dwo; base = idx - 3932160; }
    const int i = base * 4;
    float4 x = *(const float4*)(src + i);
    ushort4v o;
    o.x = f2bf(x.x); o.y = f2bf(x.y); o.z = f2bf(x.z); o.w = f2bf(x.w);
    *(ushort4v*)(dst + i) = o;
}

// ---------------- GEMM core 64x128 (2-phase prefetch) — used by out-proj & fallback ----------------
#define GEMM_BODY(A, W)                                                                             \
    constexpr int K = 1024;                                                                         \
    __shared__ unsigned short Asb[2][64 * 32];                                                      \
    __shared__ unsigned short Bsb[2][128 * 32];                                                     \
    const int t = threadIdx.x;                                                                      \
    const int w = t >> 6, l = t & 63;                                                               \
    const int wr = w >> 1, wc = w & 1;                                                              \
    const int fr = l & 15, fg = l >> 4;                                                             \
    const int m0 = blockIdx.y * 64, n0 = blockIdx.x * 128;                                          \
    const int ra = t >> 2, qa = (t & 3) * 8;                                                        \
    const int c1 = 256 + t, rb1 = c1 >> 2, qb1 = (c1 & 3) * 8;                                      \
    f32x4 acc[2][4] = {};                                                                           \
    GLDS(A + (size_t)(m0 + ra) * K + qa, &Asb[0][t * 8]);                                           \
    GLDS(W + (size_t)(n0 + ra) * K + qa, &Bsb[0][t * 8]);                                           \
    GLDS(W + (size_t)(n0 + rb1) * K + qb1, &Bsb[0][c1 * 8]);                                        \
    for (int t2 = 0; t2 < 32; ++t2) {                                                               \
        const int cur = t2 & 1;                                                                     \
        if (t2 < 31) {                                                                              \
            const int kb = (t2 + 1) * 32;                                                           \
            GLDS(A + (size_t)(m0 + ra) * K + kb + qa, &Asb[cur ^ 1][t * 8]);                        \
            GLDS(W + (size_t)(n0 + ra) * K + kb + qa, &Bsb[cur ^ 1][t * 8]);                        \
            GLDS(W + (size_t)(n0 + rb1) * K + kb + qb1, &Bsb[cur ^ 1][c1 * 8]);                     \
            asm volatile("s_waitcnt vmcnt(3)" ::: "memory");                                        \
        } else {                                                                                    \
            asm volatile("s_waitcnt vmcnt(0)" ::: "memory");                                        \
        }                                                                                           \
        __syncthreads();                                                                            \
        bf16x8 af[2], bfv[4];                                                                       \
        _Pragma("unroll") for (int mi = 0; mi < 2; mi++)                                            \
            af[mi] = *(const bf16x8*)(&Asb[cur][(wr * 32 + mi * 16 + fr) * 32 + fg * 8]);           \
        _Pragma("unroll") for (int ni = 0; ni < 4; ni++)                                            \
            bfv[ni] = *(const bf16x8*)(&Bsb[cur][(wc * 64 + ni * 16 + fr) * 32 + fg * 8]);          \
        _Pragma("unroll") for (int mi = 0; mi < 2; mi++)                                            \
            _Pragma("unroll") for (int ni = 0; ni < 4; ni++)                                        \
                acc[mi][ni] = __builtin_amdgcn_mfma_f32_16x16x32_bf16(af[mi], bfv[ni], acc[mi][ni], 0, 0, 0); \
        __syncthreads();                                                                            \
    }

// MODE 0: bf16 out [B,NH,S,HD]; MODE 1: fp32 out [M,N]; MODE 2: [B,NH,HD,S] k-permuted
template <int MODE>
__global__ __launch_bounds__(256) void gemm_bt(const unsigned short* __restrict__ A,
                                               const unsigned short* __restrict__ W,
                                               const float* __restrict__ bias,
                                               void* __restrict__ Cout) {
    GEMM_BODY(A, W)
#pragma unroll
    for (int ni = 0; ni < 4; ni++) {
        const int n = n0 + wc * 64 + ni * 16 + fr;
        const float bv = bias[n];
#pragma unroll
        for (int mi = 0; mi < 2; mi++) {
            const int mb = m0 + wr * 32 + mi * 16 + fg * 4;
            if constexpr (MODE == 1) {
                float* C = (float*)Cout;
#pragma unroll
                for (int r = 0; r < 4; r++) C[(size_t)(mb + r) * 1024 + n] = acc[mi][ni][r] + bv;
            } else if constexpr (MODE == 0) {
                unsigned short* C = (unsigned short*)Cout;
                const int h = n >> 6, hd = n & 63;
#pragma unroll
                for (int r = 0; r < 4; r++) {
                    const int m = mb + r;
                    const int bb = m >> 11, s = m & 2047;
                    C[(size_t)((bb * 16 + h) * 2048 + s) * 64 + hd] = f2bf(acc[mi][ni][r] + bv);
                }
            } else {
                unsigned short* C = (unsigned short*)Cout;
                const int h = n >> 6, hd = n & 63;
                const int bb = mb >> 11, s = mb & 2047;
                const int blk = s >> 6, off = s & 63;
                const int pos = blk * 64 + (off >> 5) * 32 + ((off & 15) >> 2) * 8 + ((off >> 4) & 1) * 4;
                ushort4v pk;
                pk.x = f2bf(acc[mi][ni][0] + bv);
                pk.y = f2bf(acc[mi][ni][1] + bv);
                pk.z = f2bf(acc[mi][ni][2] + bv);
                pk.w = f2bf(acc[mi][ni][3] + bv);
                *(ushort4v*)(C + (size_t)((bb * 16 + h) * 64 + hd) * 2048 + pos) = pk;
            }
        }
    }
}

// ---------------- fused QKV GEMM, 128x128 tile, 2-phase prefetch, counted vmcnt ----------------
__global__ __launch_bounds__(256) void gemm_qkv(const unsigned short* __restrict__ Aq,
                                                const unsigned short* __restrict__ Ak,
                                                const unsigned short* __restrict__ Av,
                                                const unsigned short* __restrict__ Wq,
                                                const unsigned short* __restrict__ Wk,
                                                const unsigned short* __restrict__ Wv,
                                                const float* __restrict__ bq,
                                                const float* __restrict__ bk,
                                                const float* __restrict__ bv_,
                                                unsigned short* __restrict__ qh,
                                                unsigned short* __restrict__ kh,
                                                unsigned short* __restrict__ vt) {
    constexpr int K = 1024;
    __shared__ unsigned short Asb[2][128 * 32];
    __shared__ unsigned short Bsb[2][128 * 32];
    const int z = blockIdx.z;
    const unsigned short* A = (z == 0) ? Aq : (z == 1) ? Ak : Av;
    const unsigned short* W = (z == 0) ? Wq : (z == 1) ? Wk : Wv;
    const float* bias = (z == 0) ? bq : (z == 1) ? bk : bv_;

    const int t = threadIdx.x;
    const int w = t >> 6, l = t & 63;
    const int wr = w >> 1, wc = w & 1;
    const int fr = l & 15, fg = l >> 4;
    const int m0 = blockIdx.y * 128, n0 = blockIdx.x * 128;

    const int c0 = t, c1 = 256 + t;
    const int r0 = c0 >> 2, q0off = (c0 & 3) * 8;
    const int r1 = c1 >> 2, q1off = (c1 & 3) * 8;

    f32x4 acc[4][4] = {};

#define STG128(kb, pb)                                                        \
    {                                                                         \
        GLDS(A + (size_t)(m0 + r0) * K + (kb) + q0off, &Asb[pb][c0 * 8]);     \
        GLDS(A + (size_t)(m0 + r1) * K + (kb) + q1off, &Asb[pb][c1 * 8]);     \
        GLDS(W + (size_t)(n0 + r0) * K + (kb) + q0off, &Bsb[pb][c0 * 8]);     \
        GLDS(W + (size_t)(n0 + r1) * K + (kb) + q1off, &Bsb[pb][c1 * 8]);     \
    }

    STG128(0, 0);
    for (int t2 = 0; t2 < 32; ++t2) {
        const int cur = t2 & 1;
        if (t2 < 31) {
            STG128((t2 + 1) * 32, cur ^ 1);
            asm volatile("s_waitcnt vmcnt(4)" ::: "memory");
        } else {
            asm volatile("s_waitcnt vmcnt(0)" ::: "memory");
        }
        __syncthreads();
        bf16x8 af[4], bfv[4];
#pragma unroll
        for (int mi = 0; mi < 4; mi++)
            af[mi] = *(const bf16x8*)(&Asb[cur][(wr * 64 + mi * 16 + fr) * 32 + fg * 8]);
#pragma unroll
        for (int ni = 0; ni < 4; ni++)
            bfv[ni] = *(const bf16x8*)(&Bsb[cur][(wc * 64 + ni * 16 + fr) * 32 + fg * 8]);
#pragma unroll
        for (int mi = 0; mi < 4; mi++)
#pragma unroll
            for (int ni = 0; ni < 4; ni++)
                acc[mi][ni] = __builtin_amdgcn_mfma_f32_16x16x32_bf16(af[mi], bfv[ni], acc[mi][ni], 0, 0, 0);
        __syncthreads();
    }
#undef STG128

#pragma unroll
    for (int ni = 0; ni < 4; ni++) {
        const int n = n0 + wc * 64 + ni * 16 + fr;
        const float bv = bias[n];
        const int h = n >> 6, hd = n & 63;
#pragma unroll
        for (int mi = 0; mi < 4; mi++) {
            const int mb = m0 + wr * 64 + mi * 16 + fg * 4;
            if (z == 2) {  // vt, k-permuted (zero-shuffle PV layout)
                const int bb = mb >> 11, s = mb & 2047;
                const int blk = s >> 6, off = s & 63;
                const int pos = blk * 64 + (off >> 5) * 32 + ((off & 15) >> 2) * 8 + ((off >> 4) & 1) * 4;
                ushort4v pk;
                pk.x = f2bf(acc[mi][ni][0] + bv);
                pk.y = f2bf(acc[mi][ni][1] + bv);
                pk.z = f2bf(acc[mi][ni][2] + bv);
                pk.w = f2bf(acc[mi][ni][3] + bv);
                *(ushort4v*)(vt + (size_t)((bb * 16 + h) * 64 + hd) * 2048 + pos) = pk;
            } else {
                unsigned short* C = (z == 0) ? qh : kh;
#pragma unroll
                for (int r = 0; r < 4; r++) {
                    const int m = mb + r;
                    const int bb = m >> 11, s = m & 2047;
                    C[(size_t)((bb * 16 + h) * 2048 + s) * 64 + hd] = f2bf(acc[mi][ni][r] + bv);
                }
            }
        }
    }
}

// ---------------- fused attention v13: 2 qt tiles per block (L2-warm K/V reuse) ----------------
// Grid 1024: bh = i>>5, qtg = i&31; block processes qt = qtg*2 + {0,1} sequentially.
// Tile 1 warms the XCD L2 with this head's K/V (512 KB); tile 2 reads hit L2.
// Inner structure identical to R12 (one-pass, P in VGPRs, interleaved nt-stores + PV).
__global__ __launch_bounds__(256, 2) void attn_kernel(const unsigned short* __restrict__ Qh,
                                                      const unsigned short* __restrict__ Kh,
                                                      const unsigned short* __restrict__ Vt,
                                                      unsigned short* __restrict__ Obuf,
                                                      float* __restrict__ AttnOut) {
    __shared__ float rpart[32][4];
    __shared__ float rinv_s[32];
    __shared__ float ored[32][68];

    const int i = blockIdx.x;
    const int qtg = i & 31, bh = i >> 5;
    const int b = bh >> 4, h = bh & 15;
    const int t = threadIdx.x, w = t >> 6, l = t & 63;
    const int fr = l & 15, fg = l >> 4;
    const float SCL = 0.1803368801111f;          // 0.125 / ln(2)

    const unsigned short* kbase = Kh + ((size_t)bh * 2048 + w * 512) * 64;
    const unsigned short* vtb = Vt + (size_t)bh * 64 * 2048;
    const unsigned short* vwb = vtb + w * 512;

#pragma unroll 1
    for (int it = 0; it < 2; ++it) {
        const int q0 = (qtg * 2 + it) * 32;

        const unsigned short* qb = Qh + (size_t)(bh * 2048 + q0) * 64;
        bf16x8 qf[2][2];
#pragma unroll
        for (int qs = 0; qs < 2; qs++)
#pragma unroll
            for (int kc = 0; kc < 2; kc++)
                qf[qs][kc] = *(const bf16x8*)(qb + (size_t)(qs * 16 + fr) * 64 + kc * 32 + fg * 8);

        // ---- phase 1: single QK^T sweep, unnormalized exp packed bf16 in regs + row-sums ----
        unsigned p0[8][8], p1[8][8];
        float rs0 = 0.f, rs1 = 0.f;
#pragma unroll
        for (int kt = 0; kt < 8; ++kt) {
#pragma unroll
            for (int mt = 0; mt < 4; ++mt) {
                const unsigned short* kr = kbase + (size_t)(kt * 64 + mt * 16 + fr) * 64 + fg * 8;
                bf16x8 kf0 = *(const bf16x8*)kr;
                bf16x8 kf1 = *(const bf16x8*)(kr + 32);
                f32x4 d0 = {}, d1 = {};
                d0 = __builtin_amdgcn_mfma_f32_16x16x32_bf16(kf0, qf[0][0], d0, 0, 0, 0);
                d0 = __builtin_amdgcn_mfma_f32_16x16x32_bf16(kf1, qf[0][1], d0, 0, 0, 0);
                d1 = __builtin_amdgcn_mfma_f32_16x16x32_bf16(kf0, qf[1][0], d1, 0, 0, 0);
                d1 = __builtin_amdgcn_mfma_f32_16x16x32_bf16(kf1, qf[1][1], d1, 0, 0, 0);
                const float a0 = exp2f(d0[0] * SCL), a1 = exp2f(d0[1] * SCL);
                const float a2 = exp2f(d0[2] * SCL), a3 = exp2f(d0[3] * SCL);
                rs0 += (a0 + a1) + (a2 + a3);
                p0[kt][mt * 2] = cvtpk(a0, a1);
                p0[kt][mt * 2 + 1] = cvtpk(a2, a3);
                const float c0 = exp2f(d1[0] * SCL), c1 = exp2f(d1[1] * SCL);
                const float c2 = exp2f(d1[2] * SCL), c3 = exp2f(d1[3] * SCL);
                rs1 += (c0 + c1) + (c2 + c3);
                p1[kt][mt * 2] = cvtpk(c0, c1);
                p1[kt][mt * 2 + 1] = cvtpk(c2, c3);
            }
        }
        // ---- phase 2: rinv ----
        rs0 += __shfl_xor(rs0, 16, 64); rs0 += __shfl_xor(rs0, 32, 64);
        rs1 += __shfl_xor(rs1, 16, 64); rs1 += __shfl_xor(rs1, 32, 64);
        if (l < 16) { rpart[l][w] = rs0; rpart[l + 16][w] = rs1; }
        __syncthreads();
        if (t < 32) rinv_s[t] = 1.0f / (rpart[t][0] + rpart[t][1] + rpart[t][2] + rpart[t][3]);
        __syncthreads();
        const float ri0 = rinv_s[fr], ri1 = rinv_s[16 + fr];

        // ---- phase 3: per kt: V loads first, nt-stores, PV ----
        float* attnB0 = AttnOut + (size_t)bh * 2048 * 2048 + (size_t)(q0 + fr) * 2048 + w * 512;
        float* attnB1 = attnB0 + (size_t)16 * 2048;
        f32x4 opv[2][4] = {};
#pragma unroll
        for (int kt = 0; kt < 8; ++kt) {
            bf16x8 vf[2][4];
#pragma unroll
            for (int kc = 0; kc < 2; ++kc)
#pragma unroll
                for (int dt = 0; dt < 4; ++dt)
                    vf[kc][dt] = *(const bf16x8*)(vwb + (size_t)(dt * 16 + fr) * 2048 + kt * 64 + kc * 32 + fg * 8);
#pragma unroll
            for (int mt = 0; mt < 4; ++mt) {
                const unsigned a = p0[kt][mt * 2], aa = p0[kt][mt * 2 + 1];
                f32x4 o;
                o[0] = __uint_as_float(a << 16) * ri0;
                o[1] = __uint_as_float(a & 0xffff0000u) * ri0;
                o[2] = __uint_as_float(aa << 16) * ri0;
                o[3] = __uint_as_float(aa & 0xffff0000u) * ri0;
                __builtin_nontemporal_store(o, (f32x4*)(attnB0 + kt * 64 + mt * 16 + fg * 4));
                const unsigned c = p1[kt][mt * 2], cc = p1[kt][mt * 2 + 1];
                f32x4 o1;
                o1[0] = __uint_as_float(c << 16) * ri1;
                o1[1] = __uint_as_float(c & 0xffff0000u) * ri1;
                o1[2] = __uint_as_float(cc << 16) * ri1;
                o1[3] = __uint_as_float(cc & 0xffff0000u) * ri1;
                __builtin_nontemporal_store(o1, (f32x4*)(attnB1 + kt * 64 + mt * 16 + fg * 4));
            }
#pragma unroll
            for (int kc = 0; kc < 2; ++kc) {
                union { unsigned u[4]; bf16x8 v; } pb0, pb1;
#pragma unroll
                for (int j = 0; j < 4; j++) { pb0.u[j] = p0[kt][4 * kc + j]; pb1.u[j] = p1[kt][4 * kc + j]; }
#pragma unroll
                for (int dt = 0; dt < 4; ++dt) {
                    opv[0][dt] = __builtin_amdgcn_mfma_f32_16x16x32_bf16(vf[kc][dt], pb0.v, opv[0][dt], 0, 0, 0);
                    opv[1][dt] = __builtin_amdgcn_mfma_f32_16x16x32_bf16(vf[kc][dt], pb1.v, opv[1][dt], 0, 0, 0);
                }
            }
        }

        // ---- phase 4/5: cross-wave O reduction (wave 0 writes, others add); O *= rinv ----
        __syncthreads();
        for (int ww = 0; ww < 4; ++ww) {
            if (w == ww) {
#pragma unroll
                for (int qs = 0; qs < 2; qs++)
#pragma unroll
                    for (int dt = 0; dt < 4; dt++)
#pragma unroll
                        for (int r = 0; r < 4; r++) {
                            if (ww == 0)
                                ored[qs * 16 + fr][dt * 16 + 4 * fg + r] = opv[qs][dt][r];
                            else
                                ored[qs * 16 + fr][dt * 16 + 4 * fg + r] += opv[qs][dt][r];
                        }
            }
            __syncthreads();
        }
        {
            const int row = t >> 3, cb = (t & 7) * 8;
            const float rr = rinv_s[row];
            ushort8 pk;
#pragma unroll
            for (int j = 0; j < 8; j++) pk[j] = f2bf(ored[row][cb + j] * rr);
            *(ushort8*)(Obuf + (size_t)(b * 2048 + q0 + row) * 1024 + h * 64 + cb) = pk;
        }
    }
}

extern "C" void kernel_launch(void* const* d_in, const int* in_sizes, int n_in,
                              void* d_out, int out_size, void* d_ws, size_t ws_size,
                              hipStream_t stream) {
    const float* q = (const float*)d_in[0];
    const float* k = (const float*)d_in[1];
    const float* v = (const float*)d_in[2];
    const float* wqw = (const float*)d_in[3];
    const float* wqb = (const float*)d_in[4];
    const float* wkw = (const float*)d_in[5];
    const float* wkb = (const float*)d_in[6];
    const float* wvw = (const float*)d_in[7];
    const float* wvb = (const float*)d_in[8];
    const float* wow = (const float*)d_in[9];
    const float* wob = (const float*)d_in[10];

    float* finalOut = (float*)d_out;
    float* attnOut = finalOut + 4194304;
    char* ws = (char*)d_ws;

    const int NX = 4194304, NW = 1048576;
    dim3 gGrid(8, 64);

    if (ws_size >= 67108864ull) {
        // fused path: 4 launches
        unsigned short* qbf  = (unsigned short*)(ws);
        unsigned short* kbf  = (unsigned short*)(ws + 8388608);
        unsigned short* vbf  = (unsigned short*)(ws + 16777216);
        unsigned short* wqbf = (unsigned short*)(ws + 25165824);
        unsigned short* wkbf = (unsigned short*)(ws + 27262976);
        unsigned short* wvbf = (unsigned short*)(ws + 29360128);
        unsigned short* wobf = (unsigned short*)(ws + 31457280);
        unsigned short* qh   = (unsigned short*)(ws + 33554432);
        unsigned short* kh   = (unsigned short*)(ws + 41943040);
        unsigned short* vt   = (unsigned short*)(ws + 50331648);
        unsigned short* obuf = (unsigned short*)(ws + 58720256);

        cvt4_kernel<<<16384, 256, 0, stream>>>(q, k, v, wqw, wkw, wvw, wow,
                                               qbf, kbf, vbf, wqbf, wkbf, wvbf, wobf);
        dim3 g3(8, 32, 3);
        gemm_qkv<<<g3, 256, 0, stream>>>(qbf, kbf, vbf, wqbf, wkbf, wvbf,
                                         wqb, wkb, wvb, qh, kh, vt);
        attn_kernel<<<1024, 256, 0, stream>>>(qh, kh, vt, obuf, attnOut);
        gemm_bt<1><<<gGrid, 256, 0, stream>>>(obuf, wobf, wob, finalOut);
    } else {
        // fallback: sequential buffers
        unsigned short* xbf  = (unsigned short*)(ws);
        unsigned short* wbf  = (unsigned short*)(ws + 8388608);
        unsigned short* qh   = (unsigned short*)(ws + 10485760);
        unsigned short* kh   = (unsigned short*)(ws + 18874368);
        unsigned short* vt   = (unsigned short*)(ws + 27262976);
        unsigned short* obuf = (unsigned short*)(ws + 35651584);
        const int c2grid = (NX + NW) / 1024;

        cvt2_kernel<<<c2grid, 256, 0, stream>>>(q, xbf, NX, wqw, wbf, NW);
        gemm_bt<0><<<gGrid, 256, 0, stream>>>(xbf, wbf, wqb, qh);
        cvt2_kernel<<<c2grid, 256, 0, stream>>>(k, xbf, NX, wkw, wbf, NW);
        gemm_bt<0><<<gGrid, 256, 0, stream>>>(xbf, wbf, wkb, kh);
        cvt2_kernel<<<c2grid, 256, 0, stream>>>(v, xbf, NX, wvw, wbf, NW);
        gemm_bt<2><<<gGrid, 256, 0, stream>>>(xbf, wbf, wvb, vt);
        attn_kernel<<<1024, 256, 0, stream>>>(qh, kh, vt, obuf, attnOut);
        cvt_kernel<<<NW / 1024, 256, 0, stream>>>(wow, wbf, NW);
        gemm_bt<1><<<gGrid, 256, 0, stream>>>(obuf, wbf, wob, finalOut);
    }
}

// Round 15
// 342.545 us; speedup vs baseline: 1.0332x; 1.0332x over previous
//
#include <hip/hip_runtime.h>

typedef short bf16x8 __attribute__((ext_vector_type(8)));      // 8 bf16 in 4 VGPRs
typedef float f32x4 __attribute__((ext_vector_type(4)));
typedef unsigned short ushort4v __attribute__((ext_vector_type(4)));
typedef unsigned short ushort8 __attribute__((ext_vector_type(8)));

#define DEVI static __device__ __forceinline__

DEVI unsigned short f2bf(float f) {               // RTNE fp32 -> bf16
    unsigned u = __float_as_uint(f);
    u += 0x7FFFu + ((u >> 16) & 1u);
    return (unsigned short)(u >> 16);
}

DEVI unsigned cvtpk(float lo, float hi) {         // packed fp32x2 -> bf16x2 (RNE)
    unsigned r;
    asm("v_cvt_pk_bf16_f32 %0, %1, %2" : "=v"(r) : "v"(lo), "v"(hi));
    return r;
}

typedef __attribute__((address_space(3))) unsigned int* lds_ptr_t;
typedef const __attribute__((address_space(1))) unsigned int* gbl_ptr_t;
#define GLDS(gp, lp) __builtin_amdgcn_global_load_lds((gbl_ptr_t)(gp), (lds_ptr_t)(lp), 16, 0, 0)

// ---------------- fp32 -> bf16 converts ----------------
__global__ void cvt_kernel(const float* __restrict__ src, unsigned short* __restrict__ dst, int n) {
    int i = (blockIdx.x * 256 + threadIdx.x) * 4;
    if (i >= n) return;
    float4 v = *(const float4*)(src + i);
    ushort4v o;
    o.x = f2bf(v.x); o.y = f2bf(v.y); o.z = f2bf(v.z); o.w = f2bf(v.w);
    *(ushort4v*)(dst + i) = o;
}

__global__ void cvt2_kernel(const float* __restrict__ s0, unsigned short* __restrict__ d0, int n0,
                            const float* __restrict__ s1, unsigned short* __restrict__ d1, int n1) {
    int idx = blockIdx.x * 256 + threadIdx.x;
    const int c0 = n0 >> 2;
    const float* src; unsigned short* dst; int i;
    if (idx < c0) { src = s0; dst = d0; i = idx * 4; }
    else {
        i = (idx - c0) * 4;
        if (i >= n1) return;
        src = s1; dst = d1;
    }
    float4 v = *(const float4*)(src + i);
    ushort4v o;
    o.x = f2bf(v.x); o.y = f2bf(v.y); o.z = f2bf(v.z); o.w = f2bf(v.w);
    *(ushort4v*)(dst + i) = o;
}

// all 7 tensors in one launch
__global__ void cvt4_kernel(const float* __restrict__ q, const float* __restrict__ k,
                            const float* __restrict__ v, const float* __restrict__ wq,
                            const float* __restrict__ wk, const float* __restrict__ wv,
                            const float* __restrict__ wo, unsigned short* __restrict__ dq,
                            unsigned short* __restrict__ dk, unsigned short* __restrict__ dv,
                            unsigned short* __restrict__ dwq, unsigned short* __restrict__ dwk,
                            unsigned short* __restrict__ dwv, unsigned short* __restrict__ dwo) {
    int idx = blockIdx.x * 256 + threadIdx.x;
    const float* src; unsigned short* dst; int base;
    if (idx < 1048576) { src = q; dst = dq; base = idx; }
    else if (idx < 2097152) { src = k; dst = dk; base = idx - 1048576; }
    else if (idx < 3145728) { src = v; dst = dv; base = idx - 2097152; }
    else if (idx < 3407872) { src = wq; dst = dwq; base = idx - 3145728; }
    else if (idx < 3670016) { src = wk; dst = dwk; base = idx - 3407872; }
    else if (idx < 3932160) { src = wv; dst = dwv; base = idx - 3670016; }
    else { src = wo; dst = dwo; base = idx - 3932160; }
    const int i = base * 4;
    float4 x = *(const float4*)(src + i);
    ushort4v o;
    o.x = f2bf(x.x); o.y = f2bf(x.y); o.z = f2bf(x.z); o.w = f2bf(x.w);
    *(ushort4v*)(dst + i) = o;
}

// ---------------- GEMM core 64x128 (2-phase prefetch) — used by out-proj & fallback ----------------
#define GEMM_BODY(A, W)                                                                             \
    constexpr int K = 1024;                                                                         \
    __shared__ unsigned short Asb[2][64 * 32];                                                      \
    __shared__ unsigned short Bsb[2][128 * 32];                                                     \
    const int t = threadIdx.x;                                                                      \
    const int w = t >> 6, l = t & 63;                                                               \
    const int wr = w >> 1, wc = w & 1;                                                              \
    const int fr = l & 15, fg = l >> 4;                                                             \
    const int m0 = blockIdx.y * 64, n0 = blockIdx.x * 128;                                          \
    const int ra = t >> 2, qa = (t & 3) * 8;                                                        \
    const int c1 = 256 + t, rb1 = c1 >> 2, qb1 = (c1 & 3) * 8;                                      \
    f32x4 acc[2][4] = {};                                                                           \
    GLDS(A + (size_t)(m0 + ra) * K + qa, &Asb[0][t * 8]);                                           \
    GLDS(W + (size_t)(n0 + ra) * K + qa, &Bsb[0][t * 8]);                                           \
    GLDS(W + (size_t)(n0 + rb1) * K + qb1, &Bsb[0][c1 * 8]);                                        \
    for (int t2 = 0; t2 < 32; ++t2) {                                                               \
        const int cur = t2 & 1;                                                                     \
        if (t2 < 31) {                                                                              \
            const int kb = (t2 + 1) * 32;                                                           \
            GLDS(A + (size_t)(m0 + ra) * K + kb + qa, &Asb[cur ^ 1][t * 8]);                        \
            GLDS(W + (size_t)(n0 + ra) * K + kb + qa, &Bsb[cur ^ 1][t * 8]);                        \
            GLDS(W + (size_t)(n0 + rb1) * K + kb + qb1, &Bsb[cur ^ 1][c1 * 8]);                     \
            asm volatile("s_waitcnt vmcnt(3)" ::: "memory");                                        \
        } else {                                                                                    \
            asm volatile("s_waitcnt vmcnt(0)" ::: "memory");                                        \
        }                                                                                           \
        __syncthreads();                                                                            \
        bf16x8 af[2], bfv[4];                                                                       \
        _Pragma("unroll") for (int mi = 0; mi < 2; mi++)                                            \
            af[mi] = *(const bf16x8*)(&Asb[cur][(wr * 32 + mi * 16 + fr) * 32 + fg * 8]);           \
        _Pragma("unroll") for (int ni = 0; ni < 4; ni++)                                            \
            bfv[ni] = *(const bf16x8*)(&Bsb[cur][(wc * 64 + ni * 16 + fr) * 32 + fg * 8]);          \
        _Pragma("unroll") for (int mi = 0; mi < 2; mi++)                                            \
            _Pragma("unroll") for (int ni = 0; ni < 4; ni++)                                        \
                acc[mi][ni] = __builtin_amdgcn_mfma_f32_16x16x32_bf16(af[mi], bfv[ni], acc[mi][ni], 0, 0, 0); \
        __syncthreads();                                                                            \
    }

// MODE 0: bf16 out [B,NH,S,HD]; MODE 1: fp32 out [M,N]; MODE 2: [B,NH,HD,S] k-permuted
template <int MODE>
__global__ __launch_bounds__(256) void gemm_bt(const unsigned short* __restrict__ A,
                                               const unsigned short* __restrict__ W,
                                               const float* __restrict__ bias,
                                               void* __restrict__ Cout) {
    GEMM_BODY(A, W)
#pragma unroll
    for (int ni = 0; ni < 4; ni++) {
        const int n = n0 + wc * 64 + ni * 16 + fr;
        const float bv = bias[n];
#pragma unroll
        for (int mi = 0; mi < 2; mi++) {
            const int mb = m0 + wr * 32 + mi * 16 + fg * 4;
            if constexpr (MODE == 1) {
                float* C = (float*)Cout;
#pragma unroll
                for (int r = 0; r < 4; r++) C[(size_t)(mb + r) * 1024 + n] = acc[mi][ni][r] + bv;
            } else if constexpr (MODE == 0) {
                unsigned short* C = (unsigned short*)Cout;
                const int h = n >> 6, hd = n & 63;
#pragma unroll
                for (int r = 0; r < 4; r++) {
                    const int m = mb + r;
                    const int bb = m >> 11, s = m & 2047;
                    C[(size_t)((bb * 16 + h) * 2048 + s) * 64 + hd] = f2bf(acc[mi][ni][r] + bv);
                }
            } else {
                unsigned short* C = (unsigned short*)Cout;
                const int h = n >> 6, hd = n & 63;
                const int bb = mb >> 11, s = mb & 2047;
                const int blk = s >> 6, off = s & 63;
                const int pos = blk * 64 + (off >> 5) * 32 + ((off & 15) >> 2) * 8 + ((off >> 4) & 1) * 4;
                ushort4v pk;
                pk.x = f2bf(acc[mi][ni][0] + bv);
                pk.y = f2bf(acc[mi][ni][1] + bv);
                pk.z = f2bf(acc[mi][ni][2] + bv);
                pk.w = f2bf(acc[mi][ni][3] + bv);
                *(ushort4v*)(C + (size_t)((bb * 16 + h) * 64 + hd) * 2048 + pos) = pk;
            }
        }
    }
}

// ---------------- fused QKV GEMM, 128x128 tile, 2-phase prefetch, counted vmcnt ----------------
__global__ __launch_bounds__(256) void gemm_qkv(const unsigned short* __restrict__ Aq,
                                                const unsigned short* __restrict__ Ak,
                                                const unsigned short* __restrict__ Av,
                                                const unsigned short* __restrict__ Wq,
                                                const unsigned short* __restrict__ Wk,
                                                const unsigned short* __restrict__ Wv,
                                                const float* __restrict__ bq,
                                                const float* __restrict__ bk,
                                                const float* __restrict__ bv_,
                                                unsigned short* __restrict__ qh,
                                                unsigned short* __restrict__ kh,
                                                unsigned short* __restrict__ vt) {
    constexpr int K = 1024;
    __shared__ unsigned short Asb[2][128 * 32];
    __shared__ unsigned short Bsb[2][128 * 32];
    const int z = blockIdx.z;
    const unsigned short* A = (z == 0) ? Aq : (z == 1) ? Ak : Av;
    const unsigned short* W = (z == 0) ? Wq : (z == 1) ? Wk : Wv;
    const float* bias = (z == 0) ? bq : (z == 1) ? bk : bv_;

    const int t = threadIdx.x;
    const int w = t >> 6, l = t & 63;
    const int wr = w >> 1, wc = w & 1;
    const int fr = l & 15, fg = l >> 4;
    const int m0 = blockIdx.y * 128, n0 = blockIdx.x * 128;

    const int c0 = t, c1 = 256 + t;
    const int r0 = c0 >> 2, q0off = (c0 & 3) * 8;
    const int r1 = c1 >> 2, q1off = (c1 & 3) * 8;

    f32x4 acc[4][4] = {};

#define STG128(kb, pb)                                                        \
    {                                                                         \
        GLDS(A + (size_t)(m0 + r0) * K + (kb) + q0off, &Asb[pb][c0 * 8]);     \
        GLDS(A + (size_t)(m0 + r1) * K + (kb) + q1off, &Asb[pb][c1 * 8]);     \
        GLDS(W + (size_t)(n0 + r0) * K + (kb) + q0off, &Bsb[pb][c0 * 8]);     \
        GLDS(W + (size_t)(n0 + r1) * K + (kb) + q1off, &Bsb[pb][c1 * 8]);     \
    }

    STG128(0, 0);
    for (int t2 = 0; t2 < 32; ++t2) {
        const int cur = t2 & 1;
        if (t2 < 31) {
            STG128((t2 + 1) * 32, cur ^ 1);
            asm volatile("s_waitcnt vmcnt(4)" ::: "memory");
        } else {
            asm volatile("s_waitcnt vmcnt(0)" ::: "memory");
        }
        __syncthreads();
        bf16x8 af[4], bfv[4];
#pragma unroll
        for (int mi = 0; mi < 4; mi++)
            af[mi] = *(const bf16x8*)(&Asb[cur][(wr * 64 + mi * 16 + fr) * 32 + fg * 8]);
#pragma unroll
        for (int ni = 0; ni < 4; ni++)
            bfv[ni] = *(const bf16x8*)(&Bsb[cur][(wc * 64 + ni * 16 + fr) * 32 + fg * 8]);
#pragma unroll
        for (int mi = 0; mi < 4; mi++)
#pragma unroll
            for (int ni = 0; ni < 4; ni++)
                acc[mi][ni] = __builtin_amdgcn_mfma_f32_16x16x32_bf16(af[mi], bfv[ni], acc[mi][ni], 0, 0, 0);
        __syncthreads();
    }
#undef STG128

#pragma unroll
    for (int ni = 0; ni < 4; ni++) {
        const int n = n0 + wc * 64 + ni * 16 + fr;
        const float bv = bias[n];
        const int h = n >> 6, hd = n & 63;
#pragma unroll
        for (int mi = 0; mi < 4; mi++) {
            const int mb = m0 + wr * 64 + mi * 16 + fg * 4;
            if (z == 2) {  // vt, k-permuted (zero-shuffle PV layout)
                const int bb = mb >> 11, s = mb & 2047;
                const int blk = s >> 6, off = s & 63;
                const int pos = blk * 64 + (off >> 5) * 32 + ((off & 15) >> 2) * 8 + ((off >> 4) & 1) * 4;
                ushort4v pk;
                pk.x = f2bf(acc[mi][ni][0] + bv);
                pk.y = f2bf(acc[mi][ni][1] + bv);
                pk.z = f2bf(acc[mi][ni][2] + bv);
                pk.w = f2bf(acc[mi][ni][3] + bv);
                *(ushort4v*)(vt + (size_t)((bb * 16 + h) * 64 + hd) * 2048 + pos) = pk;
            } else {
                unsigned short* C = (z == 0) ? qh : kh;
#pragma unroll
                for (int r = 0; r < 4; r++) {
                    const int m = mb + r;
                    const int bb = m >> 11, s = m & 2047;
                    C[(size_t)((bb * 16 + h) * 2048 + s) * 64 + hd] = f2bf(acc[mi][ni][r] + bv);
                }
            }
        }
    }
}

// ---------------- fused attention v15: 8 waves (2 q-groups x 4 k-groups), 4 waves/SIMD ----------------
// QBLK=32, 512 threads. Wave (qg,kg): 16 q rows x 512 k. Per lane: 64 packed-u32 P, ~128 VGPR
// total -> launch_bounds(512,4) = 2 blocks/CU = 4 waves/SIMD (2x TLP of R12).
// Same math/layouts as R12; k-slices shared by the 2 q-groups hit L1/L2 (same CU).
__global__ __launch_bounds__(512, 4) void attn_kernel(const unsigned short* __restrict__ Qh,
                                                      const unsigned short* __restrict__ Kh,
                                                      const unsigned short* __restrict__ Vt,
                                                      unsigned short* __restrict__ Obuf,
                                                      float* __restrict__ AttnOut) {
    __shared__ float rpart[32][4];
    __shared__ float rinv_s[32];
    __shared__ float ored[32][68];

    const int i = blockIdx.x;
    const int qt = i & 63, bh = i >> 6;
    const int b = bh >> 4, h = bh & 15;
    const int q0 = qt * 32;
    const int t = threadIdx.x, w = t >> 6, l = t & 63;
    const int kg = w & 3, qg = w >> 2;
    const int fr = l & 15, fg = l >> 4;
    const float SCL = 0.1803368801111f;          // 0.125 / ln(2)

    // Q fragments (B operand): lane holds Q[q0 + qg*16 + fr][kc*32 + fg*8 + j]
    const unsigned short* qb = Qh + (size_t)(bh * 2048 + q0 + qg * 16) * 64;
    bf16x8 qf[2];
#pragma unroll
    for (int kc = 0; kc < 2; kc++)
        qf[kc] = *(const bf16x8*)(qb + (size_t)fr * 64 + kc * 32 + fg * 8);

    const unsigned short* kbase = Kh + ((size_t)bh * 2048 + kg * 512) * 64;
    const unsigned short* vwb = Vt + (size_t)bh * 64 * 2048 + kg * 512;

    // ---- phase 1: QK^T sweep, unnormalized exp packed bf16 in regs + row-sum ----
    unsigned p[8][8];
    float rs = 0.f;
#pragma unroll
    for (int kt = 0; kt < 8; ++kt) {
#pragma unroll
        for (int mt = 0; mt < 4; ++mt) {
            const unsigned short* kr = kbase + (size_t)(kt * 64 + mt * 16 + fr) * 64 + fg * 8;
            bf16x8 kf0 = *(const bf16x8*)kr;
            bf16x8 kf1 = *(const bf16x8*)(kr + 32);
            f32x4 d = {};
            d = __builtin_amdgcn_mfma_f32_16x16x32_bf16(kf0, qf[0], d, 0, 0, 0);
            d = __builtin_amdgcn_mfma_f32_16x16x32_bf16(kf1, qf[1], d, 0, 0, 0);
            const float e0 = exp2f(d[0] * SCL), e1 = exp2f(d[1] * SCL);
            const float e2 = exp2f(d[2] * SCL), e3 = exp2f(d[3] * SCL);
            rs += (e0 + e1) + (e2 + e3);
            p[kt][mt * 2] = cvtpk(e0, e1);
            p[kt][mt * 2 + 1] = cvtpk(e2, e3);
        }
    }
    // ---- phase 2: rinv (reduce over fg groups, then over 4 k-group waves) ----
    rs += __shfl_xor(rs, 16, 64);
    rs += __shfl_xor(rs, 32, 64);
    if (l < 16) rpart[qg * 16 + l][kg] = rs;
    __syncthreads();
    if (t < 32) rinv_s[t] = 1.0f / (rpart[t][0] + rpart[t][1] + rpart[t][2] + rpart[t][3]);
    __syncthreads();
    const float ri = rinv_s[qg * 16 + fr];

    // ---- phase 3: per kt: V loads first, nt-stores, PV (zero-shuffle, permuted V) ----
    float* attnB = AttnOut + (size_t)bh * 2048 * 2048 + (size_t)(q0 + qg * 16 + fr) * 2048 + kg * 512;
    f32x4 opv[4] = {};
#pragma unroll
    for (int kt = 0; kt < 8; ++kt) {
#pragma unroll
        for (int kc = 0; kc < 2; ++kc) {
            bf16x8 vf[4];
#pragma unroll
            for (int dt = 0; dt < 4; ++dt)
                vf[dt] = *(const bf16x8*)(vwb + (size_t)(dt * 16 + fr) * 2048 + kt * 64 + kc * 32 + fg * 8);
            if (kc == 0) {  // stores after first V batch is in flight
#pragma unroll
                for (int mt = 0; mt < 4; ++mt) {
                    const unsigned a = p[kt][mt * 2], aa = p[kt][mt * 2 + 1];
                    f32x4 o;
                    o[0] = __uint_as_float(a << 16) * ri;
                    o[1] = __uint_as_float(a & 0xffff0000u) * ri;
                    o[2] = __uint_as_float(aa << 16) * ri;
                    o[3] = __uint_as_float(aa & 0xffff0000u) * ri;
                    __builtin_nontemporal_store(o, (f32x4*)(attnB + kt * 64 + mt * 16 + fg * 4));
                }
            }
            union { unsigned u[4]; bf16x8 v; } pb;
#pragma unroll
            for (int j = 0; j < 4; j++) pb.u[j] = p[kt][4 * kc + j];
#pragma unroll
            for (int dt = 0; dt < 4; ++dt)
                opv[dt] = __builtin_amdgcn_mfma_f32_16x16x32_bf16(vf[dt], pb.v, opv[dt], 0, 0, 0);
        }
    }

    // ---- phase 4: cross-k-wave O reduction (q-groups write disjoint rows); O *= rinv ----
    __syncthreads();
    for (int ww = 0; ww < 4; ++ww) {
        if (kg == ww) {
#pragma unroll
            for (int dt = 0; dt < 4; dt++)
#pragma unroll
                for (int r = 0; r < 4; r++) {
                    if (ww == 0)
                        ored[qg * 16 + fr][dt * 16 + 4 * fg + r] = opv[dt][r];
                    else
                        ored[qg * 16 + fr][dt * 16 + 4 * fg + r] += opv[dt][r];
                }
        }
        __syncthreads();
    }
    {
        const int row = t >> 4, cb = (t & 15) * 4;
        const float rr = rinv_s[row];
        ushort4v pk;
#pragma unroll
        for (int j = 0; j < 4; j++) pk[j] = f2bf(ored[row][cb + j] * rr);
        *(ushort4v*)(Obuf + (size_t)(b * 2048 + q0 + row) * 1024 + h * 64 + cb) = pk;
    }
}

extern "C" void kernel_launch(void* const* d_in, const int* in_sizes, int n_in,
                              void* d_out, int out_size, void* d_ws, size_t ws_size,
                              hipStream_t stream) {
    const float* q = (const float*)d_in[0];
    const float* k = (const float*)d_in[1];
    const float* v = (const float*)d_in[2];
    const float* wqw = (const float*)d_in[3];
    const float* wqb = (const float*)d_in[4];
    const float* wkw = (const float*)d_in[5];
    const float* wkb = (const float*)d_in[6];
    const float* wvw = (const float*)d_in[7];
    const float* wvb = (const float*)d_in[8];
    const float* wow = (const float*)d_in[9];
    const float* wob = (const float*)d_in[10];

    float* finalOut = (float*)d_out;
    float* attnOut = finalOut + 4194304;
    char* ws = (char*)d_ws;

    const int NX = 4194304, NW = 1048576;
    dim3 gGrid(8, 64);

    if (ws_size >= 67108864ull) {
        // fused path: 4 launches
        unsigned short* qbf  = (unsigned short*)(ws);
        unsigned short* kbf  = (unsigned short*)(ws + 8388608);
        unsigned short* vbf  = (unsigned short*)(ws + 16777216);
        unsigned short* wqbf = (unsigned short*)(ws + 25165824);
        unsigned short* wkbf = (unsigned short*)(ws + 27262976);
        unsigned short* wvbf = (unsigned short*)(ws + 29360128);
        unsigned short* wobf = (unsigned short*)(ws + 31457280);
        unsigned short* qh   = (unsigned short*)(ws + 33554432);
        unsigned short* kh   = (unsigned short*)(ws + 41943040);
        unsigned short* vt   = (unsigned short*)(ws + 50331648);
        unsigned short* obuf = (unsigned short*)(ws + 58720256);

        cvt4_kernel<<<16384, 256, 0, stream>>>(q, k, v, wqw, wkw, wvw, wow,
                                               qbf, kbf, vbf, wqbf, wkbf, wvbf, wobf);
        dim3 g3(8, 32, 3);
        gemm_qkv<<<g3, 256, 0, stream>>>(qbf, kbf, vbf, wqbf, wkbf, wvbf,
                                         wqb, wkb, wvb, qh, kh, vt);
        attn_kernel<<<2048, 512, 0, stream>>>(qh, kh, vt, obuf, attnOut);
        gemm_bt<1><<<gGrid, 256, 0, stream>>>(obuf, wobf, wob, finalOut);
    } else {
        // fallback: sequential buffers
        unsigned short* xbf  = (unsigned short*)(ws);
        unsigned short* wbf  = (unsigned short*)(ws + 8388608);
        unsigned short* qh   = (unsigned short*)(ws + 10485760);
        unsigned short* kh   = (unsigned short*)(ws + 18874368);
        unsigned short* vt   = (unsigned short*)(ws + 27262976);
        unsigned short* obuf = (unsigned short*)(ws + 35651584);
        const int c2grid = (NX + NW) / 1024;

        cvt2_kernel<<<c2grid, 256, 0, stream>>>(q, xbf, NX, wqw, wbf, NW);
        gemm_bt<0><<<gGrid, 256, 0, stream>>>(xbf, wbf, wqb, qh);
        cvt2_kernel<<<c2grid, 256, 0, stream>>>(k, xbf, NX, wkw, wbf, NW);
        gemm_bt<0><<<gGrid, 256, 0, stream>>>(xbf, wbf, wkb, kh);
        cvt2_kernel<<<c2grid, 256, 0, stream>>>(v, xbf, NX, wvw, wbf, NW);
        gemm_bt<2><<<gGrid, 256, 0, stream>>>(xbf, wbf, wvb, vt);
        attn_kernel<<<2048, 512, 0, stream>>>(qh, kh, vt, obuf, attnOut);
        cvt_kernel<<<NW / 1024, 256, 0, stream>>>(wow, wbf, NW);
        gemm_bt<1><<<gGrid, 256, 0, stream>>>(obuf, wbf, wob, finalOut);
    }
}

// Round 16
// 268.840 us; speedup vs baseline: 1.3164x; 1.2742x over previous
//
#include <hip/hip_runtime.h>

typedef short bf16x8 __attribute__((ext_vector_type(8)));      // 8 bf16 in 4 VGPRs
typedef float f32x4 __attribute__((ext_vector_type(4)));
typedef unsigned short ushort4v __attribute__((ext_vector_type(4)));
typedef unsigned short ushort8 __attribute__((ext_vector_type(8)));

#define DEVI static __device__ __forceinline__

DEVI unsigned short f2bf(float f) {               // RTNE fp32 -> bf16
    unsigned u = __float_as_uint(f);
    u += 0x7FFFu + ((u >> 16) & 1u);
    return (unsigned short)(u >> 16);
}

DEVI unsigned cvtpk(float lo, float hi) {         // packed fp32x2 -> bf16x2 (RNE)
    unsigned r;
    asm("v_cvt_pk_bf16_f32 %0, %1, %2" : "=v"(r) : "v"(lo), "v"(hi));
    return r;
}

typedef __attribute__((address_space(3))) unsigned int* lds_ptr_t;
typedef const __attribute__((address_space(1))) unsigned int* gbl_ptr_t;
#define GLDS(gp, lp) __builtin_amdgcn_global_load_lds((gbl_ptr_t)(gp), (lds_ptr_t)(lp), 16, 0, 0)

// ---------------- fp32 -> bf16 converts ----------------
__global__ void cvt_kernel(const float* __restrict__ src, unsigned short* __restrict__ dst, int n) {
    int i = (blockIdx.x * 256 + threadIdx.x) * 4;
    if (i >= n) return;
    float4 v = *(const float4*)(src + i);
    ushort4v o;
    o.x = f2bf(v.x); o.y = f2bf(v.y); o.z = f2bf(v.z); o.w = f2bf(v.w);
    *(ushort4v*)(dst + i) = o;
}

__global__ void cvt2_kernel(const float* __restrict__ s0, unsigned short* __restrict__ d0, int n0,
                            const float* __restrict__ s1, unsigned short* __restrict__ d1, int n1) {
    int idx = blockIdx.x * 256 + threadIdx.x;
    const int c0 = n0 >> 2;
    const float* src; unsigned short* dst; int i;
    if (idx < c0) { src = s0; dst = d0; i = idx * 4; }
    else {
        i = (idx - c0) * 4;
        if (i >= n1) return;
        src = s1; dst = d1;
    }
    float4 v = *(const float4*)(src + i);
    ushort4v o;
    o.x = f2bf(v.x); o.y = f2bf(v.y); o.z = f2bf(v.z); o.w = f2bf(v.w);
    *(ushort4v*)(dst + i) = o;
}

// all 7 tensors in one launch
__global__ void cvt4_kernel(const float* __restrict__ q, const float* __restrict__ k,
                            const float* __restrict__ v, const float* __restrict__ wq,
                            const float* __restrict__ wk, const float* __restrict__ wv,
                            const float* __restrict__ wo, unsigned short* __restrict__ dq,
                            unsigned short* __restrict__ dk, unsigned short* __restrict__ dv,
                            unsigned short* __restrict__ dwq, unsigned short* __restrict__ dwk,
                            unsigned short* __restrict__ dwv, unsigned short* __restrict__ dwo) {
    int idx = blockIdx.x * 256 + threadIdx.x;
    const float* src; unsigned short* dst; int base;
    if (idx < 1048576) { src = q; dst = dq; base = idx; }
    else if (idx < 2097152) { src = k; dst = dk; base = idx - 1048576; }
    else if (idx < 3145728) { src = v; dst = dv; base = idx - 2097152; }
    else if (idx < 3407872) { src = wq; dst = dwq; base = idx - 3145728; }
    else if (idx < 3670016) { src = wk; dst = dwk; base = idx - 3407872; }
    else if (idx < 3932160) { src = wv; dst = dwv; base = idx - 3670016; }
    else { src = wo; dst = dwo; base = idx - 3932160; }
    const int i = base * 4;
    float4 x = *(const float4*)(src + i);
    ushort4v o;
    o.x = f2bf(x.x); o.y = f2bf(x.y); o.z = f2bf(x.z); o.w = f2bf(x.w);
    *(ushort4v*)(dst + i) = o;
}

// ---------------- GEMM core 64x128 (2-phase prefetch) — used by out-proj & fallback ----------------
#define GEMM_BODY(A, W)                                                                             \
    constexpr int K = 1024;                                                                         \
    __shared__ unsigned short Asb[2][64 * 32];                                                      \
    __shared__ unsigned short Bsb[2][128 * 32];                                                     \
    const int t = threadIdx.x;                                                                      \
    const int w = t >> 6, l = t & 63;                                                               \
    const int wr = w >> 1, wc = w & 1;                                                              \
    const int fr = l & 15, fg = l >> 4;                                                             \
    const int m0 = blockIdx.y * 64, n0 = blockIdx.x * 128;                                          \
    const int ra = t >> 2, qa = (t & 3) * 8;                                                        \
    const int c1 = 256 + t, rb1 = c1 >> 2, qb1 = (c1 & 3) * 8;                                      \
    f32x4 acc[2][4] = {};                                                                           \
    GLDS(A + (size_t)(m0 + ra) * K + qa, &Asb[0][t * 8]);                                           \
    GLDS(W + (size_t)(n0 + ra) * K + qa, &Bsb[0][t * 8]);                                           \
    GLDS(W + (size_t)(n0 + rb1) * K + qb1, &Bsb[0][c1 * 8]);                                        \
    for (int t2 = 0; t2 < 32; ++t2) {                                                               \
        const int cur = t2 & 1;                                                                     \
        if (t2 < 31) {                                                                              \
            const int kb = (t2 + 1) * 32;                                                           \
            GLDS(A + (size_t)(m0 + ra) * K + kb + qa, &Asb[cur ^ 1][t * 8]);                        \
            GLDS(W + (size_t)(n0 + ra) * K + kb + qa, &Bsb[cur ^ 1][t * 8]);                        \
            GLDS(W + (size_t)(n0 + rb1) * K + kb + qb1, &Bsb[cur ^ 1][c1 * 8]);                     \
            asm volatile("s_waitcnt vmcnt(3)" ::: "memory");                                        \
        } else {                                                                                    \
            asm volatile("s_waitcnt vmcnt(0)" ::: "memory");                                        \
        }                                                                                           \
        __syncthreads();                                                                            \
        bf16x8 af[2], bfv[4];                                                                       \
        _Pragma("unroll") for (int mi = 0; mi < 2; mi++)                                            \
            af[mi] = *(const bf16x8*)(&Asb[cur][(wr * 32 + mi * 16 + fr) * 32 + fg * 8]);           \
        _Pragma("unroll") for (int ni = 0; ni < 4; ni++)                                            \
            bfv[ni] = *(const bf16x8*)(&Bsb[cur][(wc * 64 + ni * 16 + fr) * 32 + fg * 8]);          \
        _Pragma("unroll") for (int mi = 0; mi < 2; mi++)                                            \
            _Pragma("unroll") for (int ni = 0; ni < 4; ni++)                                        \
                acc[mi][ni] = __builtin_amdgcn_mfma_f32_16x16x32_bf16(af[mi], bfv[ni], acc[mi][ni], 0, 0, 0); \
        __syncthreads();                                                                            \
    }

// MODE 0: bf16 out [B,NH,S,HD]; MODE 1: fp32 out [M,N]; MODE 2: [B,NH,HD,S] k-permuted
template <int MODE>
__global__ __launch_bounds__(256) void gemm_bt(const unsigned short* __restrict__ A,
                                               const unsigned short* __restrict__ W,
                                               const float* __restrict__ bias,
                                               void* __restrict__ Cout) {
    GEMM_BODY(A, W)
#pragma unroll
    for (int ni = 0; ni < 4; ni++) {
        const int n = n0 + wc * 64 + ni * 16 + fr;
        const float bv = bias[n];
#pragma unroll
        for (int mi = 0; mi < 2; mi++) {
            const int mb = m0 + wr * 32 + mi * 16 + fg * 4;
            if constexpr (MODE == 1) {
                float* C = (float*)Cout;
#pragma unroll
                for (int r = 0; r < 4; r++) C[(size_t)(mb + r) * 1024 + n] = acc[mi][ni][r] + bv;
            } else if constexpr (MODE == 0) {
                unsigned short* C = (unsigned short*)Cout;
                const int h = n >> 6, hd = n & 63;
#pragma unroll
                for (int r = 0; r < 4; r++) {
                    const int m = mb + r;
                    const int bb = m >> 11, s = m & 2047;
                    C[(size_t)((bb * 16 + h) * 2048 + s) * 64 + hd] = f2bf(acc[mi][ni][r] + bv);
                }
            } else {
                unsigned short* C = (unsigned short*)Cout;
                const int h = n >> 6, hd = n & 63;
                const int bb = mb >> 11, s = mb & 2047;
                const int blk = s >> 6, off = s & 63;
                const int pos = blk * 64 + (off >> 5) * 32 + ((off & 15) >> 2) * 8 + ((off >> 4) & 1) * 4;
                ushort4v pk;
                pk.x = f2bf(acc[mi][ni][0] + bv);
                pk.y = f2bf(acc[mi][ni][1] + bv);
                pk.z = f2bf(acc[mi][ni][2] + bv);
                pk.w = f2bf(acc[mi][ni][3] + bv);
                *(ushort4v*)(C + (size_t)((bb * 16 + h) * 64 + hd) * 2048 + pos) = pk;
            }
        }
    }
}

// ---------------- fused QKV GEMM, 128x128 tile, 2-phase prefetch, counted vmcnt ----------------
__global__ __launch_bounds__(256) void gemm_qkv(const unsigned short* __restrict__ Aq,
                                                const unsigned short* __restrict__ Ak,
                                                const unsigned short* __restrict__ Av,
                                                const unsigned short* __restrict__ Wq,
                                                const unsigned short* __restrict__ Wk,
                                                const unsigned short* __restrict__ Wv,
                                                const float* __restrict__ bq,
                                                const float* __restrict__ bk,
                                                const float* __restrict__ bv_,
                                                unsigned short* __restrict__ qh,
                                                unsigned short* __restrict__ kh,
                                                unsigned short* __restrict__ vt) {
    constexpr int K = 1024;
    __shared__ unsigned short Asb[2][128 * 32];
    __shared__ unsigned short Bsb[2][128 * 32];
    const int z = blockIdx.z;
    const unsigned short* A = (z == 0) ? Aq : (z == 1) ? Ak : Av;
    const unsigned short* W = (z == 0) ? Wq : (z == 1) ? Wk : Wv;
    const float* bias = (z == 0) ? bq : (z == 1) ? bk : bv_;

    const int t = threadIdx.x;
    const int w = t >> 6, l = t & 63;
    const int wr = w >> 1, wc = w & 1;
    const int fr = l & 15, fg = l >> 4;
    const int m0 = blockIdx.y * 128, n0 = blockIdx.x * 128;

    const int c0 = t, c1 = 256 + t;
    const int r0 = c0 >> 2, q0off = (c0 & 3) * 8;
    const int r1 = c1 >> 2, q1off = (c1 & 3) * 8;

    f32x4 acc[4][4] = {};

#define STG128(kb, pb)                                                        \
    {                                                                         \
        GLDS(A + (size_t)(m0 + r0) * K + (kb) + q0off, &Asb[pb][c0 * 8]);     \
        GLDS(A + (size_t)(m0 + r1) * K + (kb) + q1off, &Asb[pb][c1 * 8]);     \
        GLDS(W + (size_t)(n0 + r0) * K + (kb) + q0off, &Bsb[pb][c0 * 8]);     \
        GLDS(W + (size_t)(n0 + r1) * K + (kb) + q1off, &Bsb[pb][c1 * 8]);     \
    }

    STG128(0, 0);
    for (int t2 = 0; t2 < 32; ++t2) {
        const int cur = t2 & 1;
        if (t2 < 31) {
            STG128((t2 + 1) * 32, cur ^ 1);
            asm volatile("s_waitcnt vmcnt(4)" ::: "memory");
        } else {
            asm volatile("s_waitcnt vmcnt(0)" ::: "memory");
        }
        __syncthreads();
        bf16x8 af[4], bfv[4];
#pragma unroll
        for (int mi = 0; mi < 4; mi++)
            af[mi] = *(const bf16x8*)(&Asb[cur][(wr * 64 + mi * 16 + fr) * 32 + fg * 8]);
#pragma unroll
        for (int ni = 0; ni < 4; ni++)
            bfv[ni] = *(const bf16x8*)(&Bsb[cur][(wc * 64 + ni * 16 + fr) * 32 + fg * 8]);
#pragma unroll
        for (int mi = 0; mi < 4; mi++)
#pragma unroll
            for (int ni = 0; ni < 4; ni++)
                acc[mi][ni] = __builtin_amdgcn_mfma_f32_16x16x32_bf16(af[mi], bfv[ni], acc[mi][ni], 0, 0, 0);
        __syncthreads();
    }
#undef STG128

#pragma unroll
    for (int ni = 0; ni < 4; ni++) {
        const int n = n0 + wc * 64 + ni * 16 + fr;
        const float bv = bias[n];
        const int h = n >> 6, hd = n & 63;
#pragma unroll
        for (int mi = 0; mi < 4; mi++) {
            const int mb = m0 + wr * 64 + mi * 16 + fg * 4;
            if (z == 2) {  // vt, k-permuted (zero-shuffle PV layout)
                const int bb = mb >> 11, s = mb & 2047;
                const int blk = s >> 6, off = s & 63;
                const int pos = blk * 64 + (off >> 5) * 32 + ((off & 15) >> 2) * 8 + ((off >> 4) & 1) * 4;
                ushort4v pk;
                pk.x = f2bf(acc[mi][ni][0] + bv);
                pk.y = f2bf(acc[mi][ni][1] + bv);
                pk.z = f2bf(acc[mi][ni][2] + bv);
                pk.w = f2bf(acc[mi][ni][3] + bv);
                *(ushort4v*)(vt + (size_t)((bb * 16 + h) * 64 + hd) * 2048 + pos) = pk;
            } else {
                unsigned short* C = (z == 0) ? qh : kh;
#pragma unroll
                for (int r = 0; r < 4; r++) {
                    const int m = mb + r;
                    const int bb = m >> 11, s = m & 2047;
                    C[(size_t)((bb * 16 + h) * 2048 + s) * 64 + hd] = f2bf(acc[mi][ni][r] + bv);
                }
            }
        }
    }
}

// ---------------- fused attention (best measured: one-pass, P in VGPRs, store-behind V dbuf) ----------------
// Per kt order: V-loads(kt+1) -> nt-stores(kt) -> PV-MFMA(kt). QK^T computed once; unnormalized
// exp kept as packed bf16 in 128 VGPRs/lane; attn written normalized fp32 via nt-stores.
__global__ __launch_bounds__(256, 2) void attn_kernel(const unsigned short* __restrict__ Qh,
                                                      const unsigned short* __restrict__ Kh,
                                                      const unsigned short* __restrict__ Vt,
                                                      unsigned short* __restrict__ Obuf,
                                                      float* __restrict__ AttnOut) {
    __shared__ float rpart[32][4];
    __shared__ float rinv_s[32];
    __shared__ float ored[32][68];

    const int i = blockIdx.x;
    const int qt = i & 63, bh = i >> 6;
    const int b = bh >> 4, h = bh & 15;
    const int q0 = qt * 32;
    const int t = threadIdx.x, w = t >> 6, l = t & 63;
    const int fr = l & 15, fg = l >> 4;
    const float SCL = 0.1803368801111f;          // 0.125 / ln(2)

    const unsigned short* qb = Qh + (size_t)(bh * 2048 + q0) * 64;
    bf16x8 qf[2][2];
#pragma unroll
    for (int qs = 0; qs < 2; qs++)
#pragma unroll
        for (int kc = 0; kc < 2; kc++)
            qf[qs][kc] = *(const bf16x8*)(qb + (size_t)(qs * 16 + fr) * 64 + kc * 32 + fg * 8);

    const unsigned short* kbase = Kh + ((size_t)bh * 2048 + w * 512) * 64;
    const unsigned short* vtb = Vt + (size_t)bh * 64 * 2048;

    // ---- single QK^T sweep: unnormalized exp packed bf16 in regs + row-sums ----
    unsigned p0[8][8], p1[8][8];
    float rs0 = 0.f, rs1 = 0.f;
#pragma unroll
    for (int kt = 0; kt < 8; ++kt) {
#pragma unroll
        for (int mt = 0; mt < 4; ++mt) {
            const unsigned short* kr = kbase + (size_t)(kt * 64 + mt * 16 + fr) * 64 + fg * 8;
            bf16x8 kf0 = *(const bf16x8*)kr;
            bf16x8 kf1 = *(const bf16x8*)(kr + 32);
            f32x4 d0 = {}, d1 = {};
            d0 = __builtin_amdgcn_mfma_f32_16x16x32_bf16(kf0, qf[0][0], d0, 0, 0, 0);
            d0 = __builtin_amdgcn_mfma_f32_16x16x32_bf16(kf1, qf[0][1], d0, 0, 0, 0);
            d1 = __builtin_amdgcn_mfma_f32_16x16x32_bf16(kf0, qf[1][0], d1, 0, 0, 0);
            d1 = __builtin_amdgcn_mfma_f32_16x16x32_bf16(kf1, qf[1][1], d1, 0, 0, 0);
            const float a0 = exp2f(d0[0] * SCL), a1 = exp2f(d0[1] * SCL);
            const float a2 = exp2f(d0[2] * SCL), a3 = exp2f(d0[3] * SCL);
            rs0 += (a0 + a1) + (a2 + a3);
            p0[kt][mt * 2] = cvtpk(a0, a1);
            p0[kt][mt * 2 + 1] = cvtpk(a2, a3);
            const float c0 = exp2f(d1[0] * SCL), c1 = exp2f(d1[1] * SCL);
            const float c2 = exp2f(d1[2] * SCL), c3 = exp2f(d1[3] * SCL);
            rs1 += (c0 + c1) + (c2 + c3);
            p1[kt][mt * 2] = cvtpk(c0, c1);
            p1[kt][mt * 2 + 1] = cvtpk(c2, c3);
        }
    }
    // ---- rinv ----
    rs0 += __shfl_xor(rs0, 16, 64); rs0 += __shfl_xor(rs0, 32, 64);
    rs1 += __shfl_xor(rs1, 16, 64); rs1 += __shfl_xor(rs1, 32, 64);
    if (l < 16) { rpart[l][w] = rs0; rpart[l + 16][w] = rs1; }
    __syncthreads();
    if (t < 32) rinv_s[t] = 1.0f / (rpart[t][0] + rpart[t][1] + rpart[t][2] + rpart[t][3]);
    __syncthreads();
    const float ri0 = rinv_s[fr], ri1 = rinv_s[16 + fr];

    // ---- phase 3: store-behind pipeline ----
    float* attnB0 = AttnOut + (size_t)bh * 2048 * 2048 + (size_t)(q0 + fr) * 2048 + w * 512;
    float* attnB1 = attnB0 + (size_t)16 * 2048;
    const unsigned short* vwb = vtb + w * 512;
    f32x4 opv[2][4] = {};
    bf16x8 vf[2][2][4];   // [buf][kc][dt] — kt fully unrolled so indices are static

    // preload kt=0 into buf 0
#pragma unroll
    for (int kc = 0; kc < 2; ++kc)
#pragma unroll
        for (int dt = 0; dt < 4; ++dt)
            vf[0][kc][dt] = *(const bf16x8*)(vwb + (size_t)(dt * 16 + fr) * 2048 + kc * 32 + fg * 8);

#pragma unroll
    for (int kt = 0; kt < 8; ++kt) {
        const int cur = kt & 1;
        if (kt < 7) {  // V-loads for kt+1 BEFORE this kt's stores (FIFO: loads precede stores)
#pragma unroll
            for (int kc = 0; kc < 2; ++kc)
#pragma unroll
                for (int dt = 0; dt < 4; ++dt)
                    vf[cur ^ 1][kc][dt] =
                        *(const bf16x8*)(vwb + (size_t)(dt * 16 + fr) * 2048 + (kt + 1) * 64 + kc * 32 + fg * 8);
        }
#pragma unroll
        for (int mt = 0; mt < 4; ++mt) {
            const unsigned a = p0[kt][mt * 2], aa = p0[kt][mt * 2 + 1];
            f32x4 o;
            o[0] = __uint_as_float(a << 16) * ri0;
            o[1] = __uint_as_float(a & 0xffff0000u) * ri0;
            o[2] = __uint_as_float(aa << 16) * ri0;
            o[3] = __uint_as_float(aa & 0xffff0000u) * ri0;
            __builtin_nontemporal_store(o, (f32x4*)(attnB0 + kt * 64 + mt * 16 + fg * 4));
            const unsigned c = p1[kt][mt * 2], cc = p1[kt][mt * 2 + 1];
            f32x4 o1;
            o1[0] = __uint_as_float(c << 16) * ri1;
            o1[1] = __uint_as_float(c & 0xffff0000u) * ri1;
            o1[2] = __uint_as_float(cc << 16) * ri1;
            o1[3] = __uint_as_float(cc & 0xffff0000u) * ri1;
            __builtin_nontemporal_store(o1, (f32x4*)(attnB1 + kt * 64 + mt * 16 + fg * 4));
        }
#pragma unroll
        for (int kc = 0; kc < 2; ++kc) {
            union { unsigned u[4]; bf16x8 v; } pb0, pb1;
#pragma unroll
            for (int j = 0; j < 4; j++) { pb0.u[j] = p0[kt][4 * kc + j]; pb1.u[j] = p1[kt][4 * kc + j]; }
#pragma unroll
            for (int dt = 0; dt < 4; ++dt) {
                opv[0][dt] = __builtin_amdgcn_mfma_f32_16x16x32_bf16(vf[cur][kc][dt], pb0.v, opv[0][dt], 0, 0, 0);
                opv[1][dt] = __builtin_amdgcn_mfma_f32_16x16x32_bf16(vf[cur][kc][dt], pb1.v, opv[1][dt], 0, 0, 0);
            }
        }
    }

    // ---- cross-wave O reduction (wave 0 writes, others add); O *= rinv ----
    __syncthreads();
    for (int ww = 0; ww < 4; ++ww) {
        if (w == ww) {
#pragma unroll
            for (int qs = 0; qs < 2; qs++)
#pragma unroll
                for (int dt = 0; dt < 4; dt++)
#pragma unroll
                    for (int r = 0; r < 4; r++) {
                        if (ww == 0)
                            ored[qs * 16 + fr][dt * 16 + 4 * fg + r] = opv[qs][dt][r];
                        else
                            ored[qs * 16 + fr][dt * 16 + 4 * fg + r] += opv[qs][dt][r];
                    }
        }
        __syncthreads();
    }
    {
        const int row = t >> 3, cb = (t & 7) * 8;
        const float rr = rinv_s[row];
        ushort8 pk;
#pragma unroll
        for (int j = 0; j < 8; j++) pk[j] = f2bf(ored[row][cb + j] * rr);
        *(ushort8*)(Obuf + (size_t)(b * 2048 + q0 + row) * 1024 + h * 64 + cb) = pk;
    }
}

extern "C" void kernel_launch(void* const* d_in, const int* in_sizes, int n_in,
                              void* d_out, int out_size, void* d_ws, size_t ws_size,
                              hipStream_t stream) {
    const float* q = (const float*)d_in[0];
    const float* k = (const float*)d_in[1];
    const float* v = (const float*)d_in[2];
    const float* wqw = (const float*)d_in[3];
    const float* wqb = (const float*)d_in[4];
    const float* wkw = (const float*)d_in[5];
    const float* wkb = (const float*)d_in[6];
    const float* wvw = (const float*)d_in[7];
    const float* wvb = (const float*)d_in[8];
    const float* wow = (const float*)d_in[9];
    const float* wob = (const float*)d_in[10];

    float* finalOut = (float*)d_out;
    float* attnOut = finalOut + 4194304;
    char* ws = (char*)d_ws;

    const int NX = 4194304, NW = 1048576;
    dim3 gGrid(8, 64);

    if (ws_size >= 67108864ull) {
        // fused path: 4 launches
        unsigned short* qbf  = (unsigned short*)(ws);
        unsigned short* kbf  = (unsigned short*)(ws + 8388608);
        unsigned short* vbf  = (unsigned short*)(ws + 16777216);
        unsigned short* wqbf = (unsigned short*)(ws + 25165824);
        unsigned short* wkbf = (unsigned short*)(ws + 27262976);
        unsigned short* wvbf = (unsigned short*)(ws + 29360128);
        unsigned short* wobf = (unsigned short*)(ws + 31457280);
        unsigned short* qh   = (unsigned short*)(ws + 33554432);
        unsigned short* kh   = (unsigned short*)(ws + 41943040);
        unsigned short* vt   = (unsigned short*)(ws + 50331648);
        unsigned short* obuf = (unsigned short*)(ws + 58720256);

        cvt4_kernel<<<16384, 256, 0, stream>>>(q, k, v, wqw, wkw, wvw, wow,
                                               qbf, kbf, vbf, wqbf, wkbf, wvbf, wobf);
        dim3 g3(8, 32, 3);
        gemm_qkv<<<g3, 256, 0, stream>>>(qbf, kbf, vbf, wqbf, wkbf, wvbf,
                                         wqb, wkb, wvb, qh, kh, vt);
        attn_kernel<<<2048, 256, 0, stream>>>(qh, kh, vt, obuf, attnOut);
        gemm_bt<1><<<gGrid, 256, 0, stream>>>(obuf, wobf, wob, finalOut);
    } else {
        // fallback: sequential buffers
        unsigned short* xbf  = (unsigned short*)(ws);
        unsigned short* wbf  = (unsigned short*)(ws + 8388608);
        unsigned short* qh   = (unsigned short*)(ws + 10485760);
        unsigned short* kh   = (unsigned short*)(ws + 18874368);
        unsigned short* vt   = (unsigned short*)(ws + 27262976);
        unsigned short* obuf = (unsigned short*)(ws + 35651584);
        const int c2grid = (NX + NW) / 1024;

        cvt2_kernel<<<c2grid, 256, 0, stream>>>(q, xbf, NX, wqw, wbf, NW);
        gemm_bt<0><<<gGrid, 256, 0, stream>>>(xbf, wbf, wqb, qh);
        cvt2_kernel<<<c2grid, 256, 0, stream>>>(k, xbf, NX, wkw, wbf, NW);
        gemm_bt<0><<<gGrid, 256, 0, stream>>>(xbf, wbf, wkb, kh);
        cvt2_kernel<<<c2grid, 256, 0, stream>>>(v, xbf, NX, wvw, wbf, NW);
        gemm_bt<2><<<gGrid, 256, 0, stream>>>(xbf, wbf, wvb, vt);
        attn_kernel<<<2048, 256, 0, stream>>>(qh, kh, vt, obuf, attnOut);
        cvt_kernel<<<NW / 1024, 256, 0, stream>>>(wow, wbf, NW);
        gemm_bt<1><<<gGrid, 256, 0, stream>>>(obuf, wbf, wob, finalOut);
    }
}